// Round 11
// baseline (517.956 us; speedup 1.0000x reference)
//
#include <hip/hip_runtime.h>
#include <math.h>

#define N_NODES 50000
#define N_EDGES 800000
#define D_IN 64
#define D_HID 128
#define SCAN_B 256
#define N_SB ((N_NODES + SCAN_B - 1) / SCAN_B)  // 196
#define NPB 256                                  // nodes per bucket
#define NB ((N_NODES + NPB - 1) / NPB)           // 196 buckets
#define P1_BLOCKS 256
#define EPB (N_EDGES / P1_BLOCKS)                // 3125 edges per pass-1 block

typedef unsigned short u16;
typedef unsigned int u32;
typedef __attribute__((ext_vector_type(8))) short short8;
typedef __attribute__((ext_vector_type(4))) float f32x4;

union U4S8 { uint4 u; short8 s; };

__device__ __forceinline__ float bf2f(u16 u) {
    u32 x = ((u32)u) << 16;
    float f; __builtin_memcpy(&f, &x, 4); return f;
}
__device__ __forceinline__ u16 f2bf(float f) {  // round-to-nearest-even
    u32 x; __builtin_memcpy(&x, &f, 4);
    x += 0x7fffu + ((x >> 16) & 1u);
    return (u16)(x >> 16);
}
__device__ __forceinline__ u32 pk2(float a, float b) {  // pack 2 bf16 into u32
    return (u32)f2bf(a) | ((u32)f2bf(b) << 16);
}

// ============================ CSR build ============================

__global__ void count_kernel(const int* __restrict__ dst, int* __restrict__ deg, int E) {
    int i = blockIdx.x * blockDim.x + threadIdx.x;
    if (i < E) atomicAdd(&deg[dst[i]], 1);
}

__global__ __launch_bounds__(SCAN_B) void scan_reduce_kernel(const int* __restrict__ deg,
                                                             int* __restrict__ bsum) {
    __shared__ int s[SCAN_B];
    int i = blockIdx.x * SCAN_B + threadIdx.x;
    int v = (i < N_NODES) ? deg[i] : 0;
    s[threadIdx.x] = v;
    __syncthreads();
    #pragma unroll
    for (int o = SCAN_B / 2; o > 0; o >>= 1) {
        if (threadIdx.x < o) s[threadIdx.x] += s[threadIdx.x + o];
        __syncthreads();
    }
    if (threadIdx.x == 0) bsum[blockIdx.x] = s[0];
}

__global__ __launch_bounds__(SCAN_B) void scan_sums_kernel(const int* __restrict__ bsum,
                                                           int* __restrict__ boff) {
    __shared__ int s[SCAN_B];
    int t = threadIdx.x;
    int v = (t < N_SB) ? bsum[t] : 0;
    s[t] = v;
    __syncthreads();
    #pragma unroll
    for (int o = 1; o < SCAN_B; o <<= 1) {
        int u = (t >= o) ? s[t - o] : 0;
        __syncthreads();
        s[t] += u;
        __syncthreads();
    }
    if (t < N_SB) boff[t] = s[t] - v;  // exclusive
}

__global__ __launch_bounds__(SCAN_B) void scan_write_kernel(const int* __restrict__ deg,
                                                            const int* __restrict__ boff,
                                                            int* __restrict__ off) {
    __shared__ int s[SCAN_B];
    int t = threadIdx.x;
    int i = blockIdx.x * SCAN_B + t;
    int v = (i < N_NODES) ? deg[i] : 0;
    s[t] = v;
    __syncthreads();
    #pragma unroll
    for (int o = 1; o < SCAN_B; o <<= 1) {
        int u = (t >= o) ? s[t - o] : 0;
        __syncthreads();
        s[t] += u;
        __syncthreads();
    }
    int incl = s[t] + boff[blockIdx.x];
    if (i < N_NODES) off[i] = incl - v;
    if (i == N_NODES - 1) off[N_NODES] = incl;
}

// ==================== binned scatter (2-pass) ====================
__global__ void bin_init_kernel(const int* __restrict__ off, int* __restrict__ gcur) {
    int b = threadIdx.x;
    if (b < NB) gcur[b] = off[min(b * NPB, N_NODES)];
}

__global__ __launch_bounds__(256) void bin_pass1_kernel(const int* __restrict__ src,
                                                        const int* __restrict__ dst,
                                                        int* __restrict__ gcur,
                                                        int2* __restrict__ ebuf) {
    __shared__ int hist[NB];
    __shared__ int base[NB];
    const int tid = threadIdx.x;
    const int e0 = blockIdx.x * EPB, e1 = e0 + EPB;
    for (int b = tid; b < NB; b += 256) hist[b] = 0;
    __syncthreads();
    for (int i = e0 + tid; i < e1; i += 256)
        atomicAdd(&hist[dst[i] >> 8], 1);
    __syncthreads();
    for (int b = tid; b < NB; b += 256) {
        base[b] = atomicAdd(&gcur[b], hist[b]);
        hist[b] = 0;  // reuse as block-local cursor
    }
    __syncthreads();
    for (int i = e0 + tid; i < e1; i += 256) {
        int d = dst[i];
        int b = d >> 8;
        int slot = base[b] + atomicAdd(&hist[b], 1);
        ebuf[slot] = make_int2(src[i], d);
    }
}

__global__ __launch_bounds__(256) void bin_pass2_kernel(const int* __restrict__ off,
                                                        const int2* __restrict__ ebuf,
                                                        int* __restrict__ esrc) {
    __shared__ int soff[NPB];
    __shared__ int cur[NPB];
    const int b = blockIdx.x;
    const int tid = threadIdx.x;
    const int n0 = b * NPB;
    soff[tid] = off[min(n0 + tid, N_NODES)];
    cur[tid] = 0;
    __syncthreads();
    const int e0 = soff[0];
    const int e1 = off[min(n0 + NPB, N_NODES)];
    for (int i = e0 + tid; i < e1; i += 256) {
        int2 p = ebuf[i];
        int dl = p.y - n0;
        int slot = soff[dl] + atomicAdd(&cur[dl], 1);
        esrc[slot] = p.x;
    }
}

// ==================== x -> bf16 convert ====================
__global__ __launch_bounds__(256) void xcvt_kernel(const float* __restrict__ x,
                                                   u16* __restrict__ xb) {
    int i = blockIdx.x * 256 + threadIdx.x;  // one float4 per thread
    if (i < N_NODES * D_IN / 4) {
        float4 v = ((const float4*)x)[i];
        u32 lo = pk2(v.x, v.y), hi = pk2(v.z, v.w);
        ((uint2*)xb)[i] = make_uint2(lo, hi);
    }
}

// ==================== W -> bf16 MFMA B-frag layout (once, all layers) ========
__global__ __launch_bounds__(256) void wprep_kernel(const float* __restrict__ W1,
                                                    const float* __restrict__ W2,
                                                    u16* __restrict__ w1f,
                                                    u16* __restrict__ w2f) {
    const int b = blockIdx.x;      // 0..7: layer*2 + (0=W1, 1=W2)
    const int L = b >> 1;
    if ((b & 1) == 0) {
        const float* W = W1 + (size_t)L * 64 * 128;
        u16* outp = w1f + (size_t)L * 8192;
        for (int idx = threadIdx.x; idx < 1024; idx += 256) {
            int ln = idx & 63, th = idx >> 6;          // th = t*2+half
            int half = th & 1, t = th >> 1;
            int k0 = half * 32 + (ln >> 4) * 8;
            int n = t * 16 + (ln & 15);
            uint4 o;
            o.x = pk2(W[(k0 + 0) * 128 + n], W[(k0 + 1) * 128 + n]);
            o.y = pk2(W[(k0 + 2) * 128 + n], W[(k0 + 3) * 128 + n]);
            o.z = pk2(W[(k0 + 4) * 128 + n], W[(k0 + 5) * 128 + n]);
            o.w = pk2(W[(k0 + 6) * 128 + n], W[(k0 + 7) * 128 + n]);
            *(uint4*)&outp[(size_t)idx * 8] = o;
        }
    } else {
        const float* W = W2 + (size_t)L * 128 * 64;
        u16* outp = w2f + (size_t)L * 8192;
        for (int idx = threadIdx.x; idx < 1024; idx += 256) {
            int ln = idx & 63, th = idx >> 6;          // th = t*4+ks
            int ks = th & 3, t = th >> 2;
            int k0 = ks * 32 + (ln >> 4) * 8;
            int n = t * 16 + (ln & 15);
            uint4 o;
            o.x = pk2(W[(k0 + 0) * 64 + n], W[(k0 + 1) * 64 + n]);
            o.y = pk2(W[(k0 + 2) * 64 + n], W[(k0 + 3) * 64 + n]);
            o.z = pk2(W[(k0 + 4) * 64 + n], W[(k0 + 5) * 64 + n]);
            o.w = pk2(W[(k0 + 6) * 64 + n], W[(k0 + 7) * 64 + n]);
            *(uint4*)&outp[(size_t)idx * 8] = o;
        }
    }
}

// ==================== LAYER1: fused agg + GEMM1 (MFMA) + BN stats ====================
// Block handles 64 nodes: agg into LDS row tile, MFMA vs fragged W1,
// LDS-transpose epilogue + column BN stats.
#define SA1 72   // u16 stride for agg tile: 144 B (16B multiple)
#define SC1 136  // u16 stride for epilogue tile: 272 B = 17*16B
__global__ __launch_bounds__(256) void layer1_kernel(const u16* __restrict__ x,
                                                     const int* __restrict__ off,
                                                     const int* __restrict__ esrc,
                                                     const u16* __restrict__ Wf,
                                                     const float* __restrict__ bias,
                                                     u16* __restrict__ Bout,
                                                     float* __restrict__ S,
                                                     float* __restrict__ Q) {
    __shared__ u16 sC[64 * SC1];  // 17.4 KB; first used as agg tile (stride SA1)
    u16* sA = sC;
    const int tid = threadIdx.x;
    const int wave = tid >> 6, ln = tid & 63;
    const int lm = ln & 15, quad = ln >> 4;
    const int row0g = blockIdx.x * 64;

    // ---- agg phase: wave handles 16 nodes serially, lane = channel ----
    for (int t = 0; t < 16; t++) {
        int node = row0g + wave * 16 + t;
        if (node >= N_NODES) break;
        float xn = bf2f(x[(size_t)node * D_IN + ln]);  // residual
        int jb = off[node], je = off[node + 1];
        float s = 0.f, tt = 0.f;
        int j = jb;
        for (; j + 8 <= je; j += 8) {
            int idx[8];
            #pragma unroll
            for (int u = 0; u < 8; u++) idx[u] = esrc[j + u];
            u16 v[8];
            #pragma unroll
            for (int u = 0; u < 8; u++) v[u] = x[(size_t)idx[u] * D_IN + ln];
            #pragma unroll
            for (int u = 0; u < 8; u++) {
                float msg = fmaxf(bf2f(v[u]), 0.f) + 1e-7f;
                float p = __expf(msg);
                s += p;
                tt = fmaf(msg, p, tt);
            }
        }
        for (; j < je; j++) {
            int sv = esrc[j];
            float msg = fmaxf(bf2f(x[(size_t)sv * D_IN + ln]), 0.f) + 1e-7f;
            float p = __expf(msg);
            s += p;
            tt = fmaf(msg, p, tt);
        }
        float agg = tt / (s + 1e-16f);  // deg==0 -> 0
        sA[(wave * 16 + t) * SA1 + ln] = f2bf(agg + xn);
    }
    __syncthreads();

    // ---- A-frags from own LDS rows: A[m=lm][k=quad*8+j], two K=32 halves ----
    U4S8 a0, a1;
    a0.u = *(const uint4*)&sA[(wave * 16 + lm) * SA1 + quad * 8];
    a1.u = *(const uint4*)&sA[(wave * 16 + lm) * SA1 + 32 + quad * 8];
    __syncthreads();  // all waves read sA before epilogue overwrites the buffer

    f32x4 acc[8];
    #pragma unroll
    for (int t = 0; t < 8; t++) {
        float b = bias[t * 16 + lm];
        acc[t] = (f32x4){b, b, b, b};
    }
    #pragma unroll
    for (int t = 0; t < 8; t++) {
        U4S8 b0, b1;
        b0.u = *(const uint4*)&Wf[(size_t)((t * 2 + 0) * 64 + ln) * 8];
        b1.u = *(const uint4*)&Wf[(size_t)((t * 2 + 1) * 64 + ln) * 8];
        acc[t] = __builtin_amdgcn_mfma_f32_16x16x32_bf16(a0.s, b0.s, acc[t], 0, 0, 0);
        acc[t] = __builtin_amdgcn_mfma_f32_16x16x32_bf16(a1.s, b1.s, acc[t], 0, 0, 0);
    }
    // transpose through LDS (C-layout -> row-major bf16 tile)
    const int lr0 = wave * 16 + quad * 4;
    #pragma unroll
    for (int t = 0; t < 8; t++) {
        #pragma unroll
        for (int rg = 0; rg < 4; rg++)
            sC[(lr0 + rg) * SC1 + t * 16 + lm] = f2bf(acc[t][rg]);
    }
    __syncthreads();
    // coalesced vectorized store
    const int c8 = (tid & 15) * 8;
    #pragma unroll
    for (int i = 0; i < 4; i++) {
        int lr = (tid >> 4) + i * 16;
        int r = row0g + lr;
        if (r < N_NODES)
            *(uint4*)&Bout[(size_t)r * 128 + c8] = *(const uint4*)&sC[lr * SC1 + c8];
    }
    // BN stats: column scan, one atomic per column per block
    const int rlim = min(64, N_NODES - row0g);
    if (tid < 128) {
        float s = 0.f;
        #pragma unroll 8
        for (int r = 0; r < rlim; r++) s += bf2f(sC[r * SC1 + tid]);
        atomicAdd(&S[tid], s);
    } else {
        int c = tid - 128;
        float q = 0.f;
        #pragma unroll 8
        for (int r = 0; r < rlim; r++) { float v = bf2f(sC[r * SC1 + c]); q += v * v; }
        atomicAdd(&Q[c], q);
    }
}

// ==================== GEMM2 (MFMA) + fused BN finalize + LDS epilogue =========
__device__ __forceinline__ float mish_f(float v) {
    if (v > 30.f) return v;
    float u = __expf(v);
    float t = (u + 1.f) * (u + 1.f);
    return v * (t - 1.f) / (t + 1.f);  // = v * tanh(softplus(v))
}

#define SC2B 72  // u16 stride for bf16 tile: 144 B = 9*16B
#define SC2F 68  // f32 stride for fp32 tile: 272 B = 17*16B
__global__ __launch_bounds__(256) void gemm2_kernel(const u16* __restrict__ H,
                                                    const float* __restrict__ S,
                                                    const float* __restrict__ Q,
                                                    const float* __restrict__ gamma,
                                                    const float* __restrict__ beta,
                                                    const u16* __restrict__ Wf,
                                                    const float* __restrict__ bias,
                                                    float* __restrict__ outf,
                                                    u16* __restrict__ outb,
                                                    int dobf16) {
    __shared__ float sss[256];
    __shared__ __align__(16) char sCraw[64 * SC2F * 4];  // 17.4 KB
    u16* sCb = (u16*)sCraw;
    float* sCf = (float*)sCraw;
    const int tid = threadIdx.x;
    // fused BN finalize: per-channel scale/shift from global S/Q
    if (tid < 128) {
        float mean = S[tid] * (1.f / N_NODES);
        float var = fmaxf(Q[tid] * (1.f / N_NODES) - mean * mean, 0.f);
        float sc = gamma[tid] * rsqrtf(var + 1e-5f);
        sss[tid] = sc;
        sss[128 + tid] = beta[tid] - mean * sc;
    }
    __syncthreads();
    const int wave = tid >> 6, ln = tid & 63;
    const int lm = ln & 15, quad = ln >> 4;
    const int row0g = blockIdx.x * 64;
    const int row0 = row0g + wave * 16;
    const int rA = min(row0 + lm, N_NODES - 1);

    f32x4 acc[4];
    #pragma unroll
    for (int t = 0; t < 4; t++) {
        float b = bias[t * 16 + lm];
        acc[t] = (f32x4){b, b, b, b};
    }
    #pragma unroll
    for (int ks = 0; ks < 4; ks++) {
        const int k0 = ks * 32 + quad * 8;
        U4S8 h8;
        h8.u = *(const uint4*)&H[(size_t)rA * 128 + k0];
        U4S8 a;
        #pragma unroll
        for (int j2 = 0; j2 < 4; j2++) {
            int k = k0 + 2 * j2;
            float v0 = fmaxf(fmaf(bf2f((u16)h8.s[2 * j2]),     sss[k],     sss[128 + k]),     0.f);
            float v1 = fmaxf(fmaf(bf2f((u16)h8.s[2 * j2 + 1]), sss[k + 1], sss[128 + k + 1]), 0.f);
            ((u32*)&a.u)[j2] = pk2(v0, v1);
        }
        #pragma unroll
        for (int t = 0; t < 4; t++) {
            U4S8 b;
            b.u = *(const uint4*)&Wf[(size_t)((t * 4 + ks) * 64 + ln) * 8];
            acc[t] = __builtin_amdgcn_mfma_f32_16x16x32_bf16(a.s, b.s, acc[t], 0, 0, 0);
        }
    }
    const int lr0 = wave * 16 + quad * 4;
    if (dobf16) {
        #pragma unroll
        for (int t = 0; t < 4; t++) {
            #pragma unroll
            for (int rg = 0; rg < 4; rg++)
                sCb[(lr0 + rg) * SC2B + t * 16 + lm] = f2bf(mish_f(acc[t][rg]));
        }
        __syncthreads();
        const int c8 = (tid & 7) * 8;
        #pragma unroll
        for (int i = 0; i < 2; i++) {
            int lr = (tid >> 3) + i * 32;
            int r = row0g + lr;
            if (r < N_NODES)
                *(uint4*)&outb[(size_t)r * 64 + c8] = *(const uint4*)&sCb[lr * SC2B + c8];
        }
    } else {
        #pragma unroll
        for (int t = 0; t < 4; t++) {
            #pragma unroll
            for (int rg = 0; rg < 4; rg++)
                sCf[(lr0 + rg) * SC2F + t * 16 + lm] = acc[t][rg];
        }
        __syncthreads();
        const int c8 = (tid & 7) * 8;
        #pragma unroll
        for (int i = 0; i < 2; i++) {
            int lr = (tid >> 3) + i * 32;
            int r = row0g + lr;
            if (r < N_NODES) {
                *(float4*)&outf[(size_t)r * 64 + c8]     = *(const float4*)&sCf[lr * SC2F + c8];
                *(float4*)&outf[(size_t)r * 64 + c8 + 4] = *(const float4*)&sCf[lr * SC2F + c8 + 4];
            }
        }
    }
}

// ============================ launch ============================

extern "C" void kernel_launch(void* const* d_in, const int* in_sizes, int n_in,
                              void* d_out, int out_size, void* d_ws, size_t ws_size,
                              hipStream_t stream) {
    const float* x     = (const float*)d_in[0];
    const int*   ei    = (const int*)d_in[1];
    const float* W1    = (const float*)d_in[2];
    const float* b1    = (const float*)d_in[3];
    const float* gamma = (const float*)d_in[4];
    const float* beta  = (const float*)d_in[5];
    const float* W2    = (const float*)d_in[6];
    const float* b2    = (const float*)d_in[7];
    float* out = (float*)d_out;

    const int* src = ei;
    const int* dst = ei + N_EDGES;

    char* base = (char*)d_ws;
    size_t o = 0;
    auto take = [&](size_t bytes) -> char* {
        char* p = base + o;
        o = (o + bytes + 255) & ~(size_t)255;
        return p;
    };
    int* deg     = (int*)take((size_t)N_NODES * 4);
    int* off     = (int*)take((size_t)(N_NODES + 1) * 4);
    int* esrc    = (int*)take((size_t)N_EDGES * 4);
    int2* ebuf   = (int2*)take((size_t)N_EDGES * 8);
    int* bsum    = (int*)take((size_t)N_SB * 4);
    int* boff    = (int*)take((size_t)N_SB * 4);
    int* gcur    = (int*)take((size_t)NB * 4);
    float* bn    = (float*)take(1024 * 4);  // per layer: S[128] Q[128] (4 layers)
    u16* w1f     = (u16*)take((size_t)4 * 8192 * 2);  // W1 frags, 4 layers
    u16* w2f     = (u16*)take((size_t)4 * 8192 * 2);  // W2 frags, 4 layers
    u16* xbuf    = (u16*)take((size_t)N_NODES * D_IN * 2);   // bf16 hidden state
    u16* h1buf   = (u16*)take((size_t)N_NODES * D_HID * 2);  // bf16 mid activations

    // CSR build (once per call; dst is layer-invariant)
    hipMemsetAsync(deg, 0, (size_t)N_NODES * 4, stream);
    hipMemsetAsync(bn, 0, 1024 * 4, stream);  // all layers' S/Q
    count_kernel<<<(N_EDGES + 255) / 256, 256, 0, stream>>>(dst, deg, N_EDGES);
    scan_reduce_kernel<<<N_SB, SCAN_B, 0, stream>>>(deg, bsum);
    scan_sums_kernel<<<1, SCAN_B, 0, stream>>>(bsum, boff);
    scan_write_kernel<<<N_SB, SCAN_B, 0, stream>>>(deg, boff, off);
    bin_init_kernel<<<1, 256, 0, stream>>>(off, gcur);
    bin_pass1_kernel<<<P1_BLOCKS, 256, 0, stream>>>(src, dst, gcur, ebuf);
    bin_pass2_kernel<<<NB, 256, 0, stream>>>(off, ebuf, esrc);
    xcvt_kernel<<<(N_NODES * D_IN / 4 + 255) / 256, 256, 0, stream>>>(x, xbuf);
    wprep_kernel<<<8, 256, 0, stream>>>(W1, W2, w1f, w2f);

    const int NBLK = (N_NODES + 63) / 64;
    for (int L = 0; L < 4; L++) {
        float* Sb = bn + L * 256;
        float* Qb = Sb + 128;
        layer1_kernel<<<NBLK, 256, 0, stream>>>(
            xbuf, off, esrc, w1f + (size_t)L * 8192, b1 + (size_t)L * D_HID, h1buf,
            Sb, Qb);
        gemm2_kernel<<<NBLK, 256, 0, stream>>>(
            h1buf, Sb, Qb, gamma + (size_t)L * D_HID, beta + (size_t)L * D_HID,
            w2f + (size_t)L * 8192, b2 + (size_t)L * D_IN,
            out, xbuf, (L < 3) ? 1 : 0);
    }
}

// Round 12
// 445.524 us; speedup vs baseline: 1.1626x; 1.1626x over previous
//
#include <hip/hip_runtime.h>
#include <math.h>

#define N_NODES 50000
#define N_EDGES 800000
#define D_IN 64
#define D_HID 128
#define SCAN_B 256
#define N_SB ((N_NODES + SCAN_B - 1) / SCAN_B)  // 196
#define NPB 256                                  // nodes per bucket
#define NB ((N_NODES + NPB - 1) / NPB)           // 196 buckets
#define P1_BLOCKS 256
#define EPB (N_EDGES / P1_BLOCKS)                // 3125 edges per pass-1 block

typedef unsigned short u16;
typedef unsigned int u32;
typedef __attribute__((ext_vector_type(8))) short short8;
typedef __attribute__((ext_vector_type(4))) float f32x4;

union U4S8 { uint4 u; short8 s; };

__device__ __forceinline__ float bf2f(u16 u) {
    u32 x = ((u32)u) << 16;
    float f; __builtin_memcpy(&f, &x, 4); return f;
}
__device__ __forceinline__ u16 f2bf(float f) {  // round-to-nearest-even
    u32 x; __builtin_memcpy(&x, &f, 4);
    x += 0x7fffu + ((x >> 16) & 1u);
    return (u16)(x >> 16);
}
__device__ __forceinline__ u32 pk2(float a, float b) {  // pack 2 bf16 into u32
    return (u32)f2bf(a) | ((u32)f2bf(b) << 16);
}

// ============================ CSR build ============================

__global__ void count_kernel(const int* __restrict__ dst, int* __restrict__ deg, int E) {
    int i = blockIdx.x * blockDim.x + threadIdx.x;
    if (i < E) atomicAdd(&deg[dst[i]], 1);
}

__global__ __launch_bounds__(SCAN_B) void scan_reduce_kernel(const int* __restrict__ deg,
                                                             int* __restrict__ bsum) {
    __shared__ int s[SCAN_B];
    int i = blockIdx.x * SCAN_B + threadIdx.x;
    int v = (i < N_NODES) ? deg[i] : 0;
    s[threadIdx.x] = v;
    __syncthreads();
    #pragma unroll
    for (int o = SCAN_B / 2; o > 0; o >>= 1) {
        if (threadIdx.x < o) s[threadIdx.x] += s[threadIdx.x + o];
        __syncthreads();
    }
    if (threadIdx.x == 0) bsum[blockIdx.x] = s[0];
}

__global__ __launch_bounds__(SCAN_B) void scan_sums_kernel(const int* __restrict__ bsum,
                                                           int* __restrict__ boff) {
    __shared__ int s[SCAN_B];
    int t = threadIdx.x;
    int v = (t < N_SB) ? bsum[t] : 0;
    s[t] = v;
    __syncthreads();
    #pragma unroll
    for (int o = 1; o < SCAN_B; o <<= 1) {
        int u = (t >= o) ? s[t - o] : 0;
        __syncthreads();
        s[t] += u;
        __syncthreads();
    }
    if (t < N_SB) boff[t] = s[t] - v;  // exclusive
}

__global__ __launch_bounds__(SCAN_B) void scan_write_kernel(const int* __restrict__ deg,
                                                            const int* __restrict__ boff,
                                                            int* __restrict__ off) {
    __shared__ int s[SCAN_B];
    int t = threadIdx.x;
    int i = blockIdx.x * SCAN_B + t;
    int v = (i < N_NODES) ? deg[i] : 0;
    s[t] = v;
    __syncthreads();
    #pragma unroll
    for (int o = 1; o < SCAN_B; o <<= 1) {
        int u = (t >= o) ? s[t - o] : 0;
        __syncthreads();
        s[t] += u;
        __syncthreads();
    }
    int incl = s[t] + boff[blockIdx.x];
    if (i < N_NODES) off[i] = incl - v;
    if (i == N_NODES - 1) off[N_NODES] = incl;
}

// ==================== binned scatter (2-pass) ====================
__global__ void bin_init_kernel(const int* __restrict__ off, int* __restrict__ gcur) {
    int b = threadIdx.x;
    if (b < NB) gcur[b] = off[min(b * NPB, N_NODES)];
}

__global__ __launch_bounds__(256) void bin_pass1_kernel(const int* __restrict__ src,
                                                        const int* __restrict__ dst,
                                                        int* __restrict__ gcur,
                                                        int2* __restrict__ ebuf) {
    __shared__ int hist[NB];
    __shared__ int base[NB];
    const int tid = threadIdx.x;
    const int e0 = blockIdx.x * EPB, e1 = e0 + EPB;
    for (int b = tid; b < NB; b += 256) hist[b] = 0;
    __syncthreads();
    for (int i = e0 + tid; i < e1; i += 256)
        atomicAdd(&hist[dst[i] >> 8], 1);
    __syncthreads();
    for (int b = tid; b < NB; b += 256) {
        base[b] = atomicAdd(&gcur[b], hist[b]);
        hist[b] = 0;  // reuse as block-local cursor
    }
    __syncthreads();
    for (int i = e0 + tid; i < e1; i += 256) {
        int d = dst[i];
        int b = d >> 8;
        int slot = base[b] + atomicAdd(&hist[b], 1);
        ebuf[slot] = make_int2(src[i], d);
    }
}

__global__ __launch_bounds__(256) void bin_pass2_kernel(const int* __restrict__ off,
                                                        const int2* __restrict__ ebuf,
                                                        int* __restrict__ esrc) {
    __shared__ int soff[NPB];
    __shared__ int cur[NPB];
    const int b = blockIdx.x;
    const int tid = threadIdx.x;
    const int n0 = b * NPB;
    soff[tid] = off[min(n0 + tid, N_NODES)];
    cur[tid] = 0;
    __syncthreads();
    const int e0 = soff[0];
    const int e1 = off[min(n0 + NPB, N_NODES)];
    for (int i = e0 + tid; i < e1; i += 256) {
        int2 p = ebuf[i];
        int dl = p.y - n0;
        int slot = soff[dl] + atomicAdd(&cur[dl], 1);
        esrc[slot] = p.x;
    }
}

// ==================== x -> bf16 convert ====================
__global__ __launch_bounds__(256) void xcvt_kernel(const float* __restrict__ x,
                                                   u16* __restrict__ xb) {
    int i = blockIdx.x * 256 + threadIdx.x;  // one float4 per thread
    if (i < N_NODES * D_IN / 4) {
        float4 v = ((const float4*)x)[i];
        u32 lo = pk2(v.x, v.y), hi = pk2(v.z, v.w);
        ((uint2*)xb)[i] = make_uint2(lo, hi);
    }
}

// ==================== W -> bf16 MFMA B-frag layout (once, all layers) ========
__global__ __launch_bounds__(256) void wprep_kernel(const float* __restrict__ W1,
                                                    const float* __restrict__ W2,
                                                    u16* __restrict__ w1f,
                                                    u16* __restrict__ w2f) {
    const int b = blockIdx.x;      // 0..7: layer*2 + (0=W1, 1=W2)
    const int L = b >> 1;
    if ((b & 1) == 0) {
        const float* W = W1 + (size_t)L * 64 * 128;
        u16* outp = w1f + (size_t)L * 8192;
        for (int idx = threadIdx.x; idx < 1024; idx += 256) {
            int ln = idx & 63, th = idx >> 6;          // th = t*2+half
            int half = th & 1, t = th >> 1;
            int k0 = half * 32 + (ln >> 4) * 8;
            int n = t * 16 + (ln & 15);
            uint4 o;
            o.x = pk2(W[(k0 + 0) * 128 + n], W[(k0 + 1) * 128 + n]);
            o.y = pk2(W[(k0 + 2) * 128 + n], W[(k0 + 3) * 128 + n]);
            o.z = pk2(W[(k0 + 4) * 128 + n], W[(k0 + 5) * 128 + n]);
            o.w = pk2(W[(k0 + 6) * 128 + n], W[(k0 + 7) * 128 + n]);
            *(uint4*)&outp[(size_t)idx * 8] = o;
        }
    } else {
        const float* W = W2 + (size_t)L * 128 * 64;
        u16* outp = w2f + (size_t)L * 8192;
        for (int idx = threadIdx.x; idx < 1024; idx += 256) {
            int ln = idx & 63, th = idx >> 6;          // th = t*4+ks
            int ks = th & 3, t = th >> 2;
            int k0 = ks * 32 + (ln >> 4) * 8;
            int n = t * 16 + (ln & 15);
            uint4 o;
            o.x = pk2(W[(k0 + 0) * 64 + n], W[(k0 + 1) * 64 + n]);
            o.y = pk2(W[(k0 + 2) * 64 + n], W[(k0 + 3) * 64 + n]);
            o.z = pk2(W[(k0 + 4) * 64 + n], W[(k0 + 5) * 64 + n]);
            o.w = pk2(W[(k0 + 6) * 64 + n], W[(k0 + 7) * 64 + n]);
            *(uint4*)&outp[(size_t)idx * 8] = o;
        }
    }
}

// ==================== softmax aggregation + residual (bf16 in/out) ============
// TWO nodes per wave, interleaved gathers: while both edge lists have >=8
// edges, 16 independent row-gathers are in flight per wave (latency fix).
// All branches wave-uniform.
__global__ __launch_bounds__(256) void agg_kernel(const u16* __restrict__ x,
                                                  const int* __restrict__ off,
                                                  const int* __restrict__ esrc,
                                                  u16* __restrict__ h) {
    int pair = blockIdx.x * 4 + (threadIdx.x >> 6);
    int lane = threadIdx.x & 63;
    int n0 = pair * 2, n1 = n0 + 1;
    if (n0 >= N_NODES) return;
    const bool has1 = (n1 < N_NODES);
    float xn0 = bf2f(x[(size_t)n0 * D_IN + lane]);
    float xn1 = has1 ? bf2f(x[(size_t)n1 * D_IN + lane]) : 0.f;
    int j0 = off[n0], e0 = off[n0 + 1];
    int j1 = has1 ? off[n1] : 0, e1 = has1 ? off[n1 + 1] : 0;
    float s0 = 0.f, t0 = 0.f, s1 = 0.f, t1 = 0.f;

    // joint phase: 16 outstanding gathers
    while (j0 + 8 <= e0 && j1 + 8 <= e1) {
        int ia[8], ib[8];
        #pragma unroll
        for (int u = 0; u < 8; u++) { ia[u] = esrc[j0 + u]; ib[u] = esrc[j1 + u]; }
        u16 va[8], vb[8];
        #pragma unroll
        for (int u = 0; u < 8; u++) va[u] = x[(size_t)ia[u] * D_IN + lane];
        #pragma unroll
        for (int u = 0; u < 8; u++) vb[u] = x[(size_t)ib[u] * D_IN + lane];
        #pragma unroll
        for (int u = 0; u < 8; u++) {
            float m0 = fmaxf(bf2f(va[u]), 0.f) + 1e-7f;
            float p0 = __expf(m0);
            s0 += p0; t0 = fmaf(m0, p0, t0);
            float m1 = fmaxf(bf2f(vb[u]), 0.f) + 1e-7f;
            float p1 = __expf(m1);
            s1 += p1; t1 = fmaf(m1, p1, t1);
        }
        j0 += 8; j1 += 8;
    }
    // drain node0
    for (; j0 + 8 <= e0; j0 += 8) {
        int idx[8];
        #pragma unroll
        for (int u = 0; u < 8; u++) idx[u] = esrc[j0 + u];
        u16 v[8];
        #pragma unroll
        for (int u = 0; u < 8; u++) v[u] = x[(size_t)idx[u] * D_IN + lane];
        #pragma unroll
        for (int u = 0; u < 8; u++) {
            float m = fmaxf(bf2f(v[u]), 0.f) + 1e-7f;
            float p = __expf(m);
            s0 += p; t0 = fmaf(m, p, t0);
        }
    }
    for (; j0 < e0; j0++) {
        float m = fmaxf(bf2f(x[(size_t)esrc[j0] * D_IN + lane]), 0.f) + 1e-7f;
        float p = __expf(m);
        s0 += p; t0 = fmaf(m, p, t0);
    }
    // drain node1
    for (; j1 + 8 <= e1; j1 += 8) {
        int idx[8];
        #pragma unroll
        for (int u = 0; u < 8; u++) idx[u] = esrc[j1 + u];
        u16 v[8];
        #pragma unroll
        for (int u = 0; u < 8; u++) v[u] = x[(size_t)idx[u] * D_IN + lane];
        #pragma unroll
        for (int u = 0; u < 8; u++) {
            float m = fmaxf(bf2f(v[u]), 0.f) + 1e-7f;
            float p = __expf(m);
            s1 += p; t1 = fmaf(m, p, t1);
        }
    }
    for (; j1 < e1; j1++) {
        float m = fmaxf(bf2f(x[(size_t)esrc[j1] * D_IN + lane]), 0.f) + 1e-7f;
        float p = __expf(m);
        s1 += p; t1 = fmaf(m, p, t1);
    }
    h[(size_t)n0 * D_IN + lane] = f2bf(t0 / (s0 + 1e-16f) + xn0);
    if (has1)
        h[(size_t)n1 * D_IN + lane] = f2bf(t1 / (s1 + 1e-16f) + xn1);
}

// ==================== GEMM1 (MFMA) + LDS-transpose epilogue + BN stats ========
// h1[M,128](bf16) = A[M,64](bf16) @ W1 + b1. 64 rows/block, 4 waves x 16 rows.
#define SC1 136  // u16 stride: 272 B = 17*16B (aligned for uint4 readback)
__global__ __launch_bounds__(256) void gemm1_kernel(const u16* __restrict__ A,
                                                    const u16* __restrict__ Wf,
                                                    const float* __restrict__ bias,
                                                    u16* __restrict__ Bout,
                                                    float* __restrict__ S,
                                                    float* __restrict__ Q) {
    __shared__ u16 sC[64 * SC1];  // 17.4 KB
    const int tid = threadIdx.x;
    const int wave = tid >> 6, ln = tid & 63;
    const int lm = ln & 15, quad = ln >> 4;
    const int row0g = blockIdx.x * 64;
    const int row0 = row0g + wave * 16;
    const int rA = min(row0 + lm, N_NODES - 1);

    // A-frags: A[m=lm][k=quad*8+j], two K=32 halves
    U4S8 a0, a1;
    a0.u = *(const uint4*)&A[(size_t)rA * 64 + quad * 8];
    a1.u = *(const uint4*)&A[(size_t)rA * 64 + 32 + quad * 8];

    f32x4 acc[8];
    #pragma unroll
    for (int t = 0; t < 8; t++) {
        float b = bias[t * 16 + lm];
        acc[t] = (f32x4){b, b, b, b};
    }
    #pragma unroll
    for (int t = 0; t < 8; t++) {
        U4S8 b0, b1;
        b0.u = *(const uint4*)&Wf[(size_t)((t * 2 + 0) * 64 + ln) * 8];
        b1.u = *(const uint4*)&Wf[(size_t)((t * 2 + 1) * 64 + ln) * 8];
        acc[t] = __builtin_amdgcn_mfma_f32_16x16x32_bf16(a0.s, b0.s, acc[t], 0, 0, 0);
        acc[t] = __builtin_amdgcn_mfma_f32_16x16x32_bf16(a1.s, b1.s, acc[t], 0, 0, 0);
    }
    // transpose through LDS (C-layout -> row-major bf16 tile)
    const int lr0 = wave * 16 + quad * 4;
    #pragma unroll
    for (int t = 0; t < 8; t++) {
        #pragma unroll
        for (int rg = 0; rg < 4; rg++)
            sC[(lr0 + rg) * SC1 + t * 16 + lm] = f2bf(acc[t][rg]);
    }
    __syncthreads();
    // coalesced vectorized store
    const int c8 = (tid & 15) * 8;
    #pragma unroll
    for (int i = 0; i < 4; i++) {
        int lr = (tid >> 4) + i * 16;
        int r = row0g + lr;
        if (r < N_NODES)
            *(uint4*)&Bout[(size_t)r * 128 + c8] = *(const uint4*)&sC[lr * SC1 + c8];
    }
    // BN stats: column scan, one atomic per column per block
    const int rlim = min(64, N_NODES - row0g);
    if (tid < 128) {
        float s = 0.f;
        #pragma unroll 8
        for (int r = 0; r < rlim; r++) s += bf2f(sC[r * SC1 + tid]);
        atomicAdd(&S[tid], s);
    } else {
        int c = tid - 128;
        float q = 0.f;
        #pragma unroll 8
        for (int r = 0; r < rlim; r++) { float v = bf2f(sC[r * SC1 + c]); q += v * v; }
        atomicAdd(&Q[c], q);
    }
}

// ==================== GEMM2 (MFMA) + fused BN finalize + LDS epilogue =========
__device__ __forceinline__ float mish_f(float v) {
    if (v > 30.f) return v;
    float u = __expf(v);
    float t = (u + 1.f) * (u + 1.f);
    return v * (t - 1.f) / (t + 1.f);  // = v * tanh(softplus(v))
}

#define SC2B 72  // u16 stride for bf16 tile: 144 B = 9*16B
#define SC2F 68  // f32 stride for fp32 tile: 272 B = 17*16B
__global__ __launch_bounds__(256) void gemm2_kernel(const u16* __restrict__ H,
                                                    const float* __restrict__ S,
                                                    const float* __restrict__ Q,
                                                    const float* __restrict__ gamma,
                                                    const float* __restrict__ beta,
                                                    const u16* __restrict__ Wf,
                                                    const float* __restrict__ bias,
                                                    float* __restrict__ outf,
                                                    u16* __restrict__ outb,
                                                    int dobf16) {
    __shared__ float sss[256];
    __shared__ __align__(16) char sCraw[64 * SC2F * 4];  // 17.4 KB
    u16* sCb = (u16*)sCraw;
    float* sCf = (float*)sCraw;
    const int tid = threadIdx.x;
    // fused BN finalize: per-channel scale/shift from global S/Q
    if (tid < 128) {
        float mean = S[tid] * (1.f / N_NODES);
        float var = fmaxf(Q[tid] * (1.f / N_NODES) - mean * mean, 0.f);
        float sc = gamma[tid] * rsqrtf(var + 1e-5f);
        sss[tid] = sc;
        sss[128 + tid] = beta[tid] - mean * sc;
    }
    __syncthreads();
    const int wave = tid >> 6, ln = tid & 63;
    const int lm = ln & 15, quad = ln >> 4;
    const int row0g = blockIdx.x * 64;
    const int row0 = row0g + wave * 16;
    const int rA = min(row0 + lm, N_NODES - 1);

    f32x4 acc[4];
    #pragma unroll
    for (int t = 0; t < 4; t++) {
        float b = bias[t * 16 + lm];
        acc[t] = (f32x4){b, b, b, b};
    }
    #pragma unroll
    for (int ks = 0; ks < 4; ks++) {
        const int k0 = ks * 32 + quad * 8;
        U4S8 h8;
        h8.u = *(const uint4*)&H[(size_t)rA * 128 + k0];
        U4S8 a;
        #pragma unroll
        for (int j2 = 0; j2 < 4; j2++) {
            int k = k0 + 2 * j2;
            float v0 = fmaxf(fmaf(bf2f((u16)h8.s[2 * j2]),     sss[k],     sss[128 + k]),     0.f);
            float v1 = fmaxf(fmaf(bf2f((u16)h8.s[2 * j2 + 1]), sss[k + 1], sss[128 + k + 1]), 0.f);
            ((u32*)&a.u)[j2] = pk2(v0, v1);
        }
        #pragma unroll
        for (int t = 0; t < 4; t++) {
            U4S8 b;
            b.u = *(const uint4*)&Wf[(size_t)((t * 4 + ks) * 64 + ln) * 8];
            acc[t] = __builtin_amdgcn_mfma_f32_16x16x32_bf16(a.s, b.s, acc[t], 0, 0, 0);
        }
    }
    const int lr0 = wave * 16 + quad * 4;
    if (dobf16) {
        #pragma unroll
        for (int t = 0; t < 4; t++) {
            #pragma unroll
            for (int rg = 0; rg < 4; rg++)
                sCb[(lr0 + rg) * SC2B + t * 16 + lm] = f2bf(mish_f(acc[t][rg]));
        }
        __syncthreads();
        const int c8 = (tid & 7) * 8;
        #pragma unroll
        for (int i = 0; i < 2; i++) {
            int lr = (tid >> 3) + i * 32;
            int r = row0g + lr;
            if (r < N_NODES)
                *(uint4*)&outb[(size_t)r * 64 + c8] = *(const uint4*)&sCb[lr * SC2B + c8];
        }
    } else {
        #pragma unroll
        for (int t = 0; t < 4; t++) {
            #pragma unroll
            for (int rg = 0; rg < 4; rg++)
                sCf[(lr0 + rg) * SC2F + t * 16 + lm] = acc[t][rg];
        }
        __syncthreads();
        const int c8 = (tid & 7) * 8;
        #pragma unroll
        for (int i = 0; i < 2; i++) {
            int lr = (tid >> 3) + i * 32;
            int r = row0g + lr;
            if (r < N_NODES) {
                *(float4*)&outf[(size_t)r * 64 + c8]     = *(const float4*)&sCf[lr * SC2F + c8];
                *(float4*)&outf[(size_t)r * 64 + c8 + 4] = *(const float4*)&sCf[lr * SC2F + c8 + 4];
            }
        }
    }
}

// ============================ launch ============================

extern "C" void kernel_launch(void* const* d_in, const int* in_sizes, int n_in,
                              void* d_out, int out_size, void* d_ws, size_t ws_size,
                              hipStream_t stream) {
    const float* x     = (const float*)d_in[0];
    const int*   ei    = (const int*)d_in[1];
    const float* W1    = (const float*)d_in[2];
    const float* b1    = (const float*)d_in[3];
    const float* gamma = (const float*)d_in[4];
    const float* beta  = (const float*)d_in[5];
    const float* W2    = (const float*)d_in[6];
    const float* b2    = (const float*)d_in[7];
    float* out = (float*)d_out;

    const int* src = ei;
    const int* dst = ei + N_EDGES;

    char* base = (char*)d_ws;
    size_t o = 0;
    auto take = [&](size_t bytes) -> char* {
        char* p = base + o;
        o = (o + bytes + 255) & ~(size_t)255;
        return p;
    };
    int* deg     = (int*)take((size_t)N_NODES * 4);
    int* off     = (int*)take((size_t)(N_NODES + 1) * 4);
    int* esrc    = (int*)take((size_t)N_EDGES * 4);
    int2* ebuf   = (int2*)take((size_t)N_EDGES * 8);
    int* bsum    = (int*)take((size_t)N_SB * 4);
    int* boff    = (int*)take((size_t)N_SB * 4);
    int* gcur    = (int*)take((size_t)NB * 4);
    float* bn    = (float*)take(1024 * 4);  // per layer: S[128] Q[128]
    u16* w1f     = (u16*)take((size_t)4 * 8192 * 2);  // W1 frags, 4 layers
    u16* w2f     = (u16*)take((size_t)4 * 8192 * 2);  // W2 frags, 4 layers
    u16* xbuf    = (u16*)take((size_t)N_NODES * D_IN * 2);   // bf16 hidden state
    u16* hbuf    = (u16*)take((size_t)N_NODES * D_IN * 2);   // bf16 agg output
    u16* h1buf   = (u16*)take((size_t)N_NODES * D_HID * 2);  // bf16 mid activations

    // CSR build (once per call; dst is layer-invariant)
    hipMemsetAsync(deg, 0, (size_t)N_NODES * 4, stream);
    hipMemsetAsync(bn, 0, 1024 * 4, stream);  // all layers' S/Q
    count_kernel<<<(N_EDGES + 255) / 256, 256, 0, stream>>>(dst, deg, N_EDGES);
    scan_reduce_kernel<<<N_SB, SCAN_B, 0, stream>>>(deg, bsum);
    scan_sums_kernel<<<1, SCAN_B, 0, stream>>>(bsum, boff);
    scan_write_kernel<<<N_SB, SCAN_B, 0, stream>>>(deg, boff, off);
    bin_init_kernel<<<1, 256, 0, stream>>>(off, gcur);
    bin_pass1_kernel<<<P1_BLOCKS, 256, 0, stream>>>(src, dst, gcur, ebuf);
    bin_pass2_kernel<<<NB, 256, 0, stream>>>(off, ebuf, esrc);
    xcvt_kernel<<<(N_NODES * D_IN / 4 + 255) / 256, 256, 0, stream>>>(x, xbuf);
    wprep_kernel<<<8, 256, 0, stream>>>(W1, W2, w1f, w2f);

    const int NBLK = (N_NODES + 63) / 64;
    const int ABLK = (N_NODES + 7) / 8;  // 2 nodes/wave, 4 waves/block
    for (int L = 0; L < 4; L++) {
        float* Sb = bn + L * 256;
        float* Qb = Sb + 128;
        agg_kernel<<<ABLK, 256, 0, stream>>>(xbuf, off, esrc, hbuf);
        gemm1_kernel<<<NBLK, 256, 0, stream>>>(
            hbuf, w1f + (size_t)L * 8192, b1 + (size_t)L * D_HID, h1buf,
            Sb, Qb);
        gemm2_kernel<<<NBLK, 256, 0, stream>>>(
            h1buf, Sb, Qb, gamma + (size_t)L * D_HID, beta + (size_t)L * D_HID,
            w2f + (size_t)L * 8192, b2 + (size_t)L * D_IN,
            out, xbuf, (L < 3) ? 1 : 0);
    }
}

// Round 14
// 444.126 us; speedup vs baseline: 1.1662x; 1.0031x over previous
//
#include <hip/hip_runtime.h>
#include <math.h>

#define N_NODES 50000
#define N_EDGES 800000
#define D_IN 64
#define D_HID 128
#define SCAN_B 256
#define N_SB ((N_NODES + SCAN_B - 1) / SCAN_B)  // 196
#define NPB 256                                  // nodes per bucket
#define NB ((N_NODES + NPB - 1) / NPB)           // 196 buckets
#define P1_BLOCKS 256
#define EPB (N_EDGES / P1_BLOCKS)                // 3125 edges per pass-1 block

typedef unsigned short u16;
typedef unsigned int u32;
typedef __attribute__((ext_vector_type(8))) short short8;
typedef __attribute__((ext_vector_type(4))) float f32x4;

union U4S8 { uint4 u; short8 s; };

__device__ __forceinline__ float bf2f(u16 u) {
    u32 x = ((u32)u) << 16;
    float f; __builtin_memcpy(&f, &x, 4); return f;
}
__device__ __forceinline__ u16 f2bf(float f) {  // round-to-nearest-even
    u32 x; __builtin_memcpy(&x, &f, 4);
    x += 0x7fffu + ((x >> 16) & 1u);
    return (u16)(x >> 16);
}
__device__ __forceinline__ u32 pk2(float a, float b) {  // pack 2 bf16 into u32
    return (u32)f2bf(a) | ((u32)f2bf(b) << 16);
}

// ============================ CSR build ============================

__global__ void count_kernel(const int* __restrict__ dst, int* __restrict__ deg, int E) {
    int i = blockIdx.x * blockDim.x + threadIdx.x;
    if (i < E) atomicAdd(&deg[dst[i]], 1);
}

__global__ __launch_bounds__(SCAN_B) void scan_reduce_kernel(const int* __restrict__ deg,
                                                             int* __restrict__ bsum) {
    __shared__ int s[SCAN_B];
    int i = blockIdx.x * SCAN_B + threadIdx.x;
    int v = (i < N_NODES) ? deg[i] : 0;
    s[threadIdx.x] = v;
    __syncthreads();
    #pragma unroll
    for (int o = SCAN_B / 2; o > 0; o >>= 1) {
        if (threadIdx.x < o) s[threadIdx.x] += s[threadIdx.x + o];
        __syncthreads();
    }
    if (threadIdx.x == 0) bsum[blockIdx.x] = s[0];
}

__global__ __launch_bounds__(SCAN_B) void scan_sums_kernel(const int* __restrict__ bsum,
                                                           int* __restrict__ boff) {
    __shared__ int s[SCAN_B];
    int t = threadIdx.x;
    int v = (t < N_SB) ? bsum[t] : 0;
    s[t] = v;
    __syncthreads();
    #pragma unroll
    for (int o = 1; o < SCAN_B; o <<= 1) {
        int u = (t >= o) ? s[t - o] : 0;
        __syncthreads();
        s[t] += u;
        __syncthreads();
    }
    if (t < N_SB) boff[t] = s[t] - v;  // exclusive
}

__global__ __launch_bounds__(SCAN_B) void scan_write_kernel(const int* __restrict__ deg,
                                                            const int* __restrict__ boff,
                                                            int* __restrict__ off) {
    __shared__ int s[SCAN_B];
    int t = threadIdx.x;
    int i = blockIdx.x * SCAN_B + t;
    int v = (i < N_NODES) ? deg[i] : 0;
    s[t] = v;
    __syncthreads();
    #pragma unroll
    for (int o = 1; o < SCAN_B; o <<= 1) {
        int u = (t >= o) ? s[t - o] : 0;
        __syncthreads();
        s[t] += u;
        __syncthreads();
    }
    int incl = s[t] + boff[blockIdx.x];
    if (i < N_NODES) off[i] = incl - v;
    if (i == N_NODES - 1) off[N_NODES] = incl;
}

// ==================== binned scatter (2-pass) ====================
__global__ void bin_init_kernel(const int* __restrict__ off, int* __restrict__ gcur) {
    int b = threadIdx.x;
    if (b < NB) gcur[b] = off[min(b * NPB, N_NODES)];
}

__global__ __launch_bounds__(256) void bin_pass1_kernel(const int* __restrict__ src,
                                                        const int* __restrict__ dst,
                                                        int* __restrict__ gcur,
                                                        int2* __restrict__ ebuf) {
    __shared__ int hist[NB];
    __shared__ int base[NB];
    const int tid = threadIdx.x;
    const int e0 = blockIdx.x * EPB, e1 = e0 + EPB;
    for (int b = tid; b < NB; b += 256) hist[b] = 0;
    __syncthreads();
    for (int i = e0 + tid; i < e1; i += 256)
        atomicAdd(&hist[dst[i] >> 8], 1);
    __syncthreads();
    for (int b = tid; b < NB; b += 256) {
        base[b] = atomicAdd(&gcur[b], hist[b]);
        hist[b] = 0;  // reuse as block-local cursor
    }
    __syncthreads();
    for (int i = e0 + tid; i < e1; i += 256) {
        int d = dst[i];
        int b = d >> 8;
        int slot = base[b] + atomicAdd(&hist[b], 1);
        ebuf[slot] = make_int2(src[i], d);
    }
}

__global__ __launch_bounds__(256) void bin_pass2_kernel(const int* __restrict__ off,
                                                        const int2* __restrict__ ebuf,
                                                        int* __restrict__ esrc) {
    __shared__ int soff[NPB];
    __shared__ int cur[NPB];
    const int b = blockIdx.x;
    const int tid = threadIdx.x;
    const int n0 = b * NPB;
    soff[tid] = off[min(n0 + tid, N_NODES)];
    cur[tid] = 0;
    __syncthreads();
    const int e0 = soff[0];
    const int e1 = off[min(n0 + NPB, N_NODES)];
    for (int i = e0 + tid; i < e1; i += 256) {
        int2 p = ebuf[i];
        int dl = p.y - n0;
        int slot = soff[dl] + atomicAdd(&cur[dl], 1);
        esrc[slot] = p.x;
    }
}

// ==================== x -> bf16 convert ====================
__global__ __launch_bounds__(256) void xcvt_kernel(const float* __restrict__ x,
                                                   u16* __restrict__ xb) {
    int i = blockIdx.x * 256 + threadIdx.x;  // one float4 per thread
    if (i < N_NODES * D_IN / 4) {
        float4 v = ((const float4*)x)[i];
        u32 lo = pk2(v.x, v.y), hi = pk2(v.z, v.w);
        ((uint2*)xb)[i] = make_uint2(lo, hi);
    }
}

// ==================== W -> bf16 MFMA B-frag layout (once, all layers) ========
__global__ __launch_bounds__(256) void wprep_kernel(const float* __restrict__ W1,
                                                    const float* __restrict__ W2,
                                                    u16* __restrict__ w1f,
                                                    u16* __restrict__ w2f) {
    const int b = blockIdx.x;      // 0..7: layer*2 + (0=W1, 1=W2)
    const int L = b >> 1;
    if ((b & 1) == 0) {
        const float* W = W1 + (size_t)L * 64 * 128;
        u16* outp = w1f + (size_t)L * 8192;
        for (int idx = threadIdx.x; idx < 1024; idx += 256) {
            int ln = idx & 63, th = idx >> 6;          // th = t*2+half
            int half = th & 1, t = th >> 1;
            int k0 = half * 32 + (ln >> 4) * 8;
            int n = t * 16 + (ln & 15);
            uint4 o;
            o.x = pk2(W[(k0 + 0) * 128 + n], W[(k0 + 1) * 128 + n]);
            o.y = pk2(W[(k0 + 2) * 128 + n], W[(k0 + 3) * 128 + n]);
            o.z = pk2(W[(k0 + 4) * 128 + n], W[(k0 + 5) * 128 + n]);
            o.w = pk2(W[(k0 + 6) * 128 + n], W[(k0 + 7) * 128 + n]);
            *(uint4*)&outp[(size_t)idx * 8] = o;
        }
    } else {
        const float* W = W2 + (size_t)L * 128 * 64;
        u16* outp = w2f + (size_t)L * 8192;
        for (int idx = threadIdx.x; idx < 1024; idx += 256) {
            int ln = idx & 63, th = idx >> 6;          // th = t*4+ks
            int ks = th & 3, t = th >> 2;
            int k0 = ks * 32 + (ln >> 4) * 8;
            int n = t * 16 + (ln & 15);
            uint4 o;
            o.x = pk2(W[(k0 + 0) * 64 + n], W[(k0 + 1) * 64 + n]);
            o.y = pk2(W[(k0 + 2) * 64 + n], W[(k0 + 3) * 64 + n]);
            o.z = pk2(W[(k0 + 4) * 64 + n], W[(k0 + 5) * 64 + n]);
            o.w = pk2(W[(k0 + 6) * 64 + n], W[(k0 + 7) * 64 + n]);
            *(uint4*)&outp[(size_t)idx * 8] = o;
        }
    }
}

// ==================== softmax aggregation + residual (bf16 in/out) ============
// TWO nodes per wave, interleaved gathers: while both edge lists have >=8
// edges, 16 independent row-gathers are in flight per wave (latency fix).
// All branches wave-uniform.
__global__ __launch_bounds__(256) void agg_kernel(const u16* __restrict__ x,
                                                  const int* __restrict__ off,
                                                  const int* __restrict__ esrc,
                                                  u16* __restrict__ h) {
    int pair = blockIdx.x * 4 + (threadIdx.x >> 6);
    int lane = threadIdx.x & 63;
    int n0 = pair * 2, n1 = n0 + 1;
    if (n0 >= N_NODES) return;
    const bool has1 = (n1 < N_NODES);
    float xn0 = bf2f(x[(size_t)n0 * D_IN + lane]);
    float xn1 = has1 ? bf2f(x[(size_t)n1 * D_IN + lane]) : 0.f;
    int j0 = off[n0], e0 = off[n0 + 1];
    int j1 = has1 ? off[n1] : 0, e1 = has1 ? off[n1 + 1] : 0;
    float s0 = 0.f, t0 = 0.f, s1 = 0.f, t1 = 0.f;

    // joint phase: 16 outstanding gathers
    while (j0 + 8 <= e0 && j1 + 8 <= e1) {
        int ia[8], ib[8];
        #pragma unroll
        for (int u = 0; u < 8; u++) { ia[u] = esrc[j0 + u]; ib[u] = esrc[j1 + u]; }
        u16 va[8], vb[8];
        #pragma unroll
        for (int u = 0; u < 8; u++) va[u] = x[(size_t)ia[u] * D_IN + lane];
        #pragma unroll
        for (int u = 0; u < 8; u++) vb[u] = x[(size_t)ib[u] * D_IN + lane];
        #pragma unroll
        for (int u = 0; u < 8; u++) {
            float m0 = fmaxf(bf2f(va[u]), 0.f) + 1e-7f;
            float p0 = __expf(m0);
            s0 += p0; t0 = fmaf(m0, p0, t0);
            float m1 = fmaxf(bf2f(vb[u]), 0.f) + 1e-7f;
            float p1 = __expf(m1);
            s1 += p1; t1 = fmaf(m1, p1, t1);
        }
        j0 += 8; j1 += 8;
    }
    // drain node0
    for (; j0 + 8 <= e0; j0 += 8) {
        int idx[8];
        #pragma unroll
        for (int u = 0; u < 8; u++) idx[u] = esrc[j0 + u];
        u16 v[8];
        #pragma unroll
        for (int u = 0; u < 8; u++) v[u] = x[(size_t)idx[u] * D_IN + lane];
        #pragma unroll
        for (int u = 0; u < 8; u++) {
            float m = fmaxf(bf2f(v[u]), 0.f) + 1e-7f;
            float p = __expf(m);
            s0 += p; t0 = fmaf(m, p, t0);
        }
    }
    for (; j0 < e0; j0++) {
        float m = fmaxf(bf2f(x[(size_t)esrc[j0] * D_IN + lane]), 0.f) + 1e-7f;
        float p = __expf(m);
        s0 += p; t0 = fmaf(m, p, t0);
    }
    // drain node1
    for (; j1 + 8 <= e1; j1 += 8) {
        int idx[8];
        #pragma unroll
        for (int u = 0; u < 8; u++) idx[u] = esrc[j1 + u];
        u16 v[8];
        #pragma unroll
        for (int u = 0; u < 8; u++) v[u] = x[(size_t)idx[u] * D_IN + lane];
        #pragma unroll
        for (int u = 0; u < 8; u++) {
            float m = fmaxf(bf2f(v[u]), 0.f) + 1e-7f;
            float p = __expf(m);
            s1 += p; t1 = fmaf(m, p, t1);
        }
    }
    for (; j1 < e1; j1++) {
        float m = fmaxf(bf2f(x[(size_t)esrc[j1] * D_IN + lane]), 0.f) + 1e-7f;
        float p = __expf(m);
        s1 += p; t1 = fmaf(m, p, t1);
    }
    h[(size_t)n0 * D_IN + lane] = f2bf(t0 / (s0 + 1e-16f) + xn0);
    if (has1)
        h[(size_t)n1 * D_IN + lane] = f2bf(t1 / (s1 + 1e-16f) + xn1);
}

// ==================== GEMM1 (MFMA) + LDS-transpose epilogue + BN stats ========
// h1[M,128](bf16) = A[M,64](bf16) @ W1 + b1. 64 rows/block, 4 waves x 16 rows.
#define SC1 136  // u16 stride: 272 B = 17*16B (aligned for uint4 readback)
__global__ __launch_bounds__(256) void gemm1_kernel(const u16* __restrict__ A,
                                                    const u16* __restrict__ Wf,
                                                    const float* __restrict__ bias,
                                                    u16* __restrict__ Bout,
                                                    float* __restrict__ S,
                                                    float* __restrict__ Q) {
    __shared__ u16 sC[64 * SC1];  // 17.4 KB
    const int tid = threadIdx.x;
    const int wave = tid >> 6, ln = tid & 63;
    const int lm = ln & 15, quad = ln >> 4;
    const int row0g = blockIdx.x * 64;
    const int row0 = row0g + wave * 16;
    const int rA = min(row0 + lm, N_NODES - 1);

    // A-frags: A[m=lm][k=quad*8+j], two K=32 halves
    U4S8 a0, a1;
    a0.u = *(const uint4*)&A[(size_t)rA * 64 + quad * 8];
    a1.u = *(const uint4*)&A[(size_t)rA * 64 + 32 + quad * 8];

    f32x4 acc[8];
    #pragma unroll
    for (int t = 0; t < 8; t++) {
        float b = bias[t * 16 + lm];
        acc[t] = (f32x4){b, b, b, b};
    }
    #pragma unroll
    for (int t = 0; t < 8; t++) {
        U4S8 b0, b1;
        b0.u = *(const uint4*)&Wf[(size_t)((t * 2 + 0) * 64 + ln) * 8];
        b1.u = *(const uint4*)&Wf[(size_t)((t * 2 + 1) * 64 + ln) * 8];
        acc[t] = __builtin_amdgcn_mfma_f32_16x16x32_bf16(a0.s, b0.s, acc[t], 0, 0, 0);
        acc[t] = __builtin_amdgcn_mfma_f32_16x16x32_bf16(a1.s, b1.s, acc[t], 0, 0, 0);
    }
    // transpose through LDS (C-layout -> row-major bf16 tile)
    const int lr0 = wave * 16 + quad * 4;
    #pragma unroll
    for (int t = 0; t < 8; t++) {
        #pragma unroll
        for (int rg = 0; rg < 4; rg++)
            sC[(lr0 + rg) * SC1 + t * 16 + lm] = f2bf(acc[t][rg]);
    }
    __syncthreads();
    // coalesced vectorized store
    const int c8 = (tid & 15) * 8;
    #pragma unroll
    for (int i = 0; i < 4; i++) {
        int lr = (tid >> 4) + i * 16;
        int r = row0g + lr;
        if (r < N_NODES)
            *(uint4*)&Bout[(size_t)r * 128 + c8] = *(const uint4*)&sC[lr * SC1 + c8];
    }
    // BN stats: column scan, one atomic per column per block
    const int rlim = min(64, N_NODES - row0g);
    if (tid < 128) {
        float s = 0.f;
        #pragma unroll 8
        for (int r = 0; r < rlim; r++) s += bf2f(sC[r * SC1 + tid]);
        atomicAdd(&S[tid], s);
    } else {
        int c = tid - 128;
        float q = 0.f;
        #pragma unroll 8
        for (int r = 0; r < rlim; r++) { float v = bf2f(sC[r * SC1 + c]); q += v * v; }
        atomicAdd(&Q[c], q);
    }
}

// ==================== GEMM2 (MFMA) + fused BN finalize + LDS epilogue =========
__device__ __forceinline__ float mish_f(float v) {
    if (v > 30.f) return v;
    float u = __expf(v);
    float t = (u + 1.f) * (u + 1.f);
    return v * (t - 1.f) / (t + 1.f);  // = v * tanh(softplus(v))
}

#define SC2B 72  // u16 stride for bf16 tile: 144 B = 9*16B
#define SC2F 68  // f32 stride for fp32 tile: 272 B = 17*16B
__global__ __launch_bounds__(256) void gemm2_kernel(const u16* __restrict__ H,
                                                    const float* __restrict__ S,
                                                    const float* __restrict__ Q,
                                                    const float* __restrict__ gamma,
                                                    const float* __restrict__ beta,
                                                    const u16* __restrict__ Wf,
                                                    const float* __restrict__ bias,
                                                    float* __restrict__ outf,
                                                    u16* __restrict__ outb,
                                                    int dobf16) {
    __shared__ float sss[256];
    __shared__ __align__(16) char sCraw[64 * SC2F * 4];  // 17.4 KB
    u16* sCb = (u16*)sCraw;
    float* sCf = (float*)sCraw;
    const int tid = threadIdx.x;
    // fused BN finalize: per-channel scale/shift from global S/Q
    if (tid < 128) {
        float mean = S[tid] * (1.f / N_NODES);
        float var = fmaxf(Q[tid] * (1.f / N_NODES) - mean * mean, 0.f);
        float sc = gamma[tid] * rsqrtf(var + 1e-5f);
        sss[tid] = sc;
        sss[128 + tid] = beta[tid] - mean * sc;
    }
    __syncthreads();
    const int wave = tid >> 6, ln = tid & 63;
    const int lm = ln & 15, quad = ln >> 4;
    const int row0g = blockIdx.x * 64;
    const int row0 = row0g + wave * 16;
    const int rA = min(row0 + lm, N_NODES - 1);

    f32x4 acc[4];
    #pragma unroll
    for (int t = 0; t < 4; t++) {
        float b = bias[t * 16 + lm];
        acc[t] = (f32x4){b, b, b, b};
    }
    #pragma unroll
    for (int ks = 0; ks < 4; ks++) {
        const int k0 = ks * 32 + quad * 8;
        U4S8 h8;
        h8.u = *(const uint4*)&H[(size_t)rA * 128 + k0];
        U4S8 a;
        #pragma unroll
        for (int j2 = 0; j2 < 4; j2++) {
            int k = k0 + 2 * j2;
            float v0 = fmaxf(fmaf(bf2f((u16)h8.s[2 * j2]),     sss[k],     sss[128 + k]),     0.f);
            float v1 = fmaxf(fmaf(bf2f((u16)h8.s[2 * j2 + 1]), sss[k + 1], sss[128 + k + 1]), 0.f);
            ((u32*)&a.u)[j2] = pk2(v0, v1);
        }
        #pragma unroll
        for (int t = 0; t < 4; t++) {
            U4S8 b;
            b.u = *(const uint4*)&Wf[(size_t)((t * 4 + ks) * 64 + ln) * 8];
            acc[t] = __builtin_amdgcn_mfma_f32_16x16x32_bf16(a.s, b.s, acc[t], 0, 0, 0);
        }
    }
    const int lr0 = wave * 16 + quad * 4;
    if (dobf16) {
        #pragma unroll
        for (int t = 0; t < 4; t++) {
            #pragma unroll
            for (int rg = 0; rg < 4; rg++)
                sCb[(lr0 + rg) * SC2B + t * 16 + lm] = f2bf(mish_f(acc[t][rg]));
        }
        __syncthreads();
        const int c8 = (tid & 7) * 8;
        #pragma unroll
        for (int i = 0; i < 2; i++) {
            int lr = (tid >> 3) + i * 32;
            int r = row0g + lr;
            if (r < N_NODES)
                *(uint4*)&outb[(size_t)r * 64 + c8] = *(const uint4*)&sCb[lr * SC2B + c8];
        }
    } else {
        #pragma unroll
        for (int t = 0; t < 4; t++) {
            #pragma unroll
            for (int rg = 0; rg < 4; rg++)
                sCf[(lr0 + rg) * SC2F + t * 16 + lm] = acc[t][rg];
        }
        __syncthreads();
        const int c8 = (tid & 7) * 8;
        #pragma unroll
        for (int i = 0; i < 2; i++) {
            int lr = (tid >> 3) + i * 32;
            int r = row0g + lr;
            if (r < N_NODES) {
                *(float4*)&outf[(size_t)r * 64 + c8]     = *(const float4*)&sCf[lr * SC2F + c8];
                *(float4*)&outf[(size_t)r * 64 + c8 + 4] = *(const float4*)&sCf[lr * SC2F + c8 + 4];
            }
        }
    }
}

// ============================ launch ============================

extern "C" void kernel_launch(void* const* d_in, const int* in_sizes, int n_in,
                              void* d_out, int out_size, void* d_ws, size_t ws_size,
                              hipStream_t stream) {
    const float* x     = (const float*)d_in[0];
    const int*   ei    = (const int*)d_in[1];
    const float* W1    = (const float*)d_in[2];
    const float* b1    = (const float*)d_in[3];
    const float* gamma = (const float*)d_in[4];
    const float* beta  = (const float*)d_in[5];
    const float* W2    = (const float*)d_in[6];
    const float* b2    = (const float*)d_in[7];
    float* out = (float*)d_out;

    const int* src = ei;
    const int* dst = ei + N_EDGES;

    char* base = (char*)d_ws;
    size_t o = 0;
    auto take = [&](size_t bytes) -> char* {
        char* p = base + o;
        o = (o + bytes + 255) & ~(size_t)255;
        return p;
    };
    int* deg     = (int*)take((size_t)N_NODES * 4);
    int* off     = (int*)take((size_t)(N_NODES + 1) * 4);
    int* esrc    = (int*)take((size_t)N_EDGES * 4);
    int2* ebuf   = (int2*)take((size_t)N_EDGES * 8);
    int* bsum    = (int*)take((size_t)N_SB * 4);
    int* boff    = (int*)take((size_t)N_SB * 4);
    int* gcur    = (int*)take((size_t)NB * 4);
    float* bn    = (float*)take(1024 * 4);  // per layer: S[128] Q[128]
    u16* w1f     = (u16*)take((size_t)4 * 8192 * 2);  // W1 frags, 4 layers
    u16* w2f     = (u16*)take((size_t)4 * 8192 * 2);  // W2 frags, 4 layers
    u16* xbuf    = (u16*)take((size_t)N_NODES * D_IN * 2);   // bf16 hidden state
    u16* hbuf    = (u16*)take((size_t)N_NODES * D_IN * 2);   // bf16 agg output
    u16* h1buf   = (u16*)take((size_t)N_NODES * D_HID * 2);  // bf16 mid activations

    // CSR build (once per call; dst is layer-invariant)
    hipMemsetAsync(deg, 0, (size_t)N_NODES * 4, stream);
    hipMemsetAsync(bn, 0, 1024 * 4, stream);  // all layers' S/Q
    count_kernel<<<(N_EDGES + 255) / 256, 256, 0, stream>>>(dst, deg, N_EDGES);
    scan_reduce_kernel<<<N_SB, SCAN_B, 0, stream>>>(deg, bsum);
    scan_sums_kernel<<<1, SCAN_B, 0, stream>>>(bsum, boff);
    scan_write_kernel<<<N_SB, SCAN_B, 0, stream>>>(deg, boff, off);
    bin_init_kernel<<<1, 256, 0, stream>>>(off, gcur);
    bin_pass1_kernel<<<P1_BLOCKS, 256, 0, stream>>>(src, dst, gcur, ebuf);
    bin_pass2_kernel<<<NB, 256, 0, stream>>>(off, ebuf, esrc);
    xcvt_kernel<<<(N_NODES * D_IN / 4 + 255) / 256, 256, 0, stream>>>(x, xbuf);
    wprep_kernel<<<8, 256, 0, stream>>>(W1, W2, w1f, w2f);

    const int NBLK = (N_NODES + 63) / 64;
    const int ABLK = (N_NODES + 7) / 8;  // 2 nodes/wave, 4 waves/block
    for (int L = 0; L < 4; L++) {
        float* Sb = bn + L * 256;
        float* Qb = Sb + 128;
        agg_kernel<<<ABLK, 256, 0, stream>>>(xbuf, off, esrc, hbuf);
        gemm1_kernel<<<NBLK, 256, 0, stream>>>(
            hbuf, w1f + (size_t)L * 8192, b1 + (size_t)L * D_HID, h1buf,
            Sb, Qb);
        gemm2_kernel<<<NBLK, 256, 0, stream>>>(
            h1buf, Sb, Qb, gamma + (size_t)L * D_HID, beta + (size_t)L * D_HID,
            w2f + (size_t)L * 8192, b2 + (size_t)L * D_IN,
            out, xbuf, (L < 3) ? 1 : 0);
    }
}

// Round 15
// 435.551 us; speedup vs baseline: 1.1892x; 1.0197x over previous
//
#include <hip/hip_runtime.h>
#include <math.h>

#define N_NODES 50000
#define N_EDGES 800000
#define D_IN 64
#define D_HID 128
#define SCAN_B 256
#define N_SB ((N_NODES + SCAN_B - 1) / SCAN_B)  // 196
#define NPB 256                                  // nodes per bucket
#define NB ((N_NODES + NPB - 1) / NPB)           // 196 buckets
#define P1_BLOCKS 256
#define EPB (N_EDGES / P1_BLOCKS)                // 3125 edges per pass-1 block

typedef unsigned short u16;
typedef unsigned int u32;
typedef __attribute__((ext_vector_type(8))) short short8;
typedef __attribute__((ext_vector_type(4))) float f32x4;

union U4S8 { uint4 u; short8 s; };

__device__ __forceinline__ float bf2f(u16 u) {
    u32 x = ((u32)u) << 16;
    float f; __builtin_memcpy(&f, &x, 4); return f;
}
__device__ __forceinline__ u16 f2bf(float f) {  // round-to-nearest-even
    u32 x; __builtin_memcpy(&x, &f, 4);
    x += 0x7fffu + ((x >> 16) & 1u);
    return (u16)(x >> 16);
}
__device__ __forceinline__ u32 pk2(float a, float b) {  // pack 2 bf16 into u32
    return (u32)f2bf(a) | ((u32)f2bf(b) << 16);
}

// ============================ CSR build ============================

__global__ void count_kernel(const int* __restrict__ dst, int* __restrict__ deg, int E) {
    int i = blockIdx.x * blockDim.x + threadIdx.x;
    if (i < E) atomicAdd(&deg[dst[i]], 1);
}

__global__ __launch_bounds__(SCAN_B) void scan_reduce_kernel(const int* __restrict__ deg,
                                                             int* __restrict__ bsum) {
    __shared__ int s[SCAN_B];
    int i = blockIdx.x * SCAN_B + threadIdx.x;
    int v = (i < N_NODES) ? deg[i] : 0;
    s[threadIdx.x] = v;
    __syncthreads();
    #pragma unroll
    for (int o = SCAN_B / 2; o > 0; o >>= 1) {
        if (threadIdx.x < o) s[threadIdx.x] += s[threadIdx.x + o];
        __syncthreads();
    }
    if (threadIdx.x == 0) bsum[blockIdx.x] = s[0];
}

__global__ __launch_bounds__(SCAN_B) void scan_sums_kernel(const int* __restrict__ bsum,
                                                           int* __restrict__ boff) {
    __shared__ int s[SCAN_B];
    int t = threadIdx.x;
    int v = (t < N_SB) ? bsum[t] : 0;
    s[t] = v;
    __syncthreads();
    #pragma unroll
    for (int o = 1; o < SCAN_B; o <<= 1) {
        int u = (t >= o) ? s[t - o] : 0;
        __syncthreads();
        s[t] += u;
        __syncthreads();
    }
    if (t < N_SB) boff[t] = s[t] - v;  // exclusive
}

__global__ __launch_bounds__(SCAN_B) void scan_write_kernel(const int* __restrict__ deg,
                                                            const int* __restrict__ boff,
                                                            int* __restrict__ off) {
    __shared__ int s[SCAN_B];
    int t = threadIdx.x;
    int i = blockIdx.x * SCAN_B + t;
    int v = (i < N_NODES) ? deg[i] : 0;
    s[t] = v;
    __syncthreads();
    #pragma unroll
    for (int o = 1; o < SCAN_B; o <<= 1) {
        int u = (t >= o) ? s[t - o] : 0;
        __syncthreads();
        s[t] += u;
        __syncthreads();
    }
    int incl = s[t] + boff[blockIdx.x];
    if (i < N_NODES) off[i] = incl - v;
    if (i == N_NODES - 1) off[N_NODES] = incl;
}

// ==================== binned scatter (2-pass) ====================
__global__ void bin_init_kernel(const int* __restrict__ off, int* __restrict__ gcur) {
    int b = threadIdx.x;
    if (b < NB) gcur[b] = off[min(b * NPB, N_NODES)];
}

__global__ __launch_bounds__(256) void bin_pass1_kernel(const int* __restrict__ src,
                                                        const int* __restrict__ dst,
                                                        int* __restrict__ gcur,
                                                        int2* __restrict__ ebuf) {
    __shared__ int hist[NB];
    __shared__ int base[NB];
    const int tid = threadIdx.x;
    const int e0 = blockIdx.x * EPB, e1 = e0 + EPB;
    for (int b = tid; b < NB; b += 256) hist[b] = 0;
    __syncthreads();
    for (int i = e0 + tid; i < e1; i += 256)
        atomicAdd(&hist[dst[i] >> 8], 1);
    __syncthreads();
    for (int b = tid; b < NB; b += 256) {
        base[b] = atomicAdd(&gcur[b], hist[b]);
        hist[b] = 0;  // reuse as block-local cursor
    }
    __syncthreads();
    for (int i = e0 + tid; i < e1; i += 256) {
        int d = dst[i];
        int b = d >> 8;
        int slot = base[b] + atomicAdd(&hist[b], 1);
        ebuf[slot] = make_int2(src[i], d);
    }
}

__global__ __launch_bounds__(256) void bin_pass2_kernel(const int* __restrict__ off,
                                                        const int2* __restrict__ ebuf,
                                                        int* __restrict__ esrc) {
    __shared__ int soff[NPB];
    __shared__ int cur[NPB];
    const int b = blockIdx.x;
    const int tid = threadIdx.x;
    const int n0 = b * NPB;
    soff[tid] = off[min(n0 + tid, N_NODES)];
    cur[tid] = 0;
    __syncthreads();
    const int e0 = soff[0];
    const int e1 = off[min(n0 + NPB, N_NODES)];
    for (int i = e0 + tid; i < e1; i += 256) {
        int2 p = ebuf[i];
        int dl = p.y - n0;
        int slot = soff[dl] + atomicAdd(&cur[dl], 1);
        esrc[slot] = p.x;
    }
}

// ==================== x -> bf16 convert ====================
__global__ __launch_bounds__(256) void xcvt_kernel(const float* __restrict__ x,
                                                   u16* __restrict__ xb) {
    int i = blockIdx.x * 256 + threadIdx.x;  // one float4 per thread
    if (i < N_NODES * D_IN / 4) {
        float4 v = ((const float4*)x)[i];
        u32 lo = pk2(v.x, v.y), hi = pk2(v.z, v.w);
        ((uint2*)xb)[i] = make_uint2(lo, hi);
    }
}

// ==================== W -> bf16 MFMA B-frag layout (once, all layers) ========
__global__ __launch_bounds__(256) void wprep_kernel(const float* __restrict__ W1,
                                                    const float* __restrict__ W2,
                                                    u16* __restrict__ w1f,
                                                    u16* __restrict__ w2f) {
    const int b = blockIdx.x;      // 0..7: layer*2 + (0=W1, 1=W2)
    const int L = b >> 1;
    if ((b & 1) == 0) {
        const float* W = W1 + (size_t)L * 64 * 128;
        u16* outp = w1f + (size_t)L * 8192;
        for (int idx = threadIdx.x; idx < 1024; idx += 256) {
            int ln = idx & 63, th = idx >> 6;          // th = t*2+half
            int half = th & 1, t = th >> 1;
            int k0 = half * 32 + (ln >> 4) * 8;
            int n = t * 16 + (ln & 15);
            uint4 o;
            o.x = pk2(W[(k0 + 0) * 128 + n], W[(k0 + 1) * 128 + n]);
            o.y = pk2(W[(k0 + 2) * 128 + n], W[(k0 + 3) * 128 + n]);
            o.z = pk2(W[(k0 + 4) * 128 + n], W[(k0 + 5) * 128 + n]);
            o.w = pk2(W[(k0 + 6) * 128 + n], W[(k0 + 7) * 128 + n]);
            *(uint4*)&outp[(size_t)idx * 8] = o;
        }
    } else {
        const float* W = W2 + (size_t)L * 128 * 64;
        u16* outp = w2f + (size_t)L * 8192;
        for (int idx = threadIdx.x; idx < 1024; idx += 256) {
            int ln = idx & 63, th = idx >> 6;          // th = t*4+ks
            int ks = th & 3, t = th >> 2;
            int k0 = ks * 32 + (ln >> 4) * 8;
            int n = t * 16 + (ln & 15);
            uint4 o;
            o.x = pk2(W[(k0 + 0) * 64 + n], W[(k0 + 1) * 64 + n]);
            o.y = pk2(W[(k0 + 2) * 64 + n], W[(k0 + 3) * 64 + n]);
            o.z = pk2(W[(k0 + 4) * 64 + n], W[(k0 + 5) * 64 + n]);
            o.w = pk2(W[(k0 + 6) * 64 + n], W[(k0 + 7) * 64 + n]);
            *(uint4*)&outp[(size_t)idx * 8] = o;
        }
    }
}

// ==================== softmax aggregation + residual (bf16 in/out) ============
// Row-vectorized gathers: lane (e=ln>>3, c8=ln&7) loads uint4 (8 channels) of
// edge e's source row -> ONE vmem instruction covers 8 edges (vs 8 before).
// Per-lane s/t accumulators over its channel slice; cross-edge shfl reduction.
__global__ __launch_bounds__(256) void agg_kernel(const u16* __restrict__ x,
                                                  const int* __restrict__ off,
                                                  const int* __restrict__ esrc,
                                                  u16* __restrict__ h) {
    const int node = blockIdx.x * 4 + (threadIdx.x >> 6);
    const int ln = threadIdx.x & 63;
    const int e = ln >> 3;        // edge slot 0..7
    const int cb = (ln & 7) * 8;  // channel base (8 channels per lane)
    if (node >= N_NODES) return;
    const int jb = off[node], je = off[node + 1];
    float s[8], t[8];
    #pragma unroll
    for (int k = 0; k < 8; k++) { s[k] = 0.f; t[k] = 0.f; }
    int j = jb;
    // main loop: 16 edges per iter, 2 gather instrs in flight (16 lines)
    for (; j + 16 <= je; j += 16) {
        int i0 = esrc[j + e];
        int i1 = esrc[j + 8 + e];
        U4S8 r0, r1;
        r0.u = *(const uint4*)&x[(size_t)i0 * D_IN + cb];
        r1.u = *(const uint4*)&x[(size_t)i1 * D_IN + cb];
        #pragma unroll
        for (int k = 0; k < 8; k++) {
            float m = fmaxf(bf2f((u16)r0.s[k]), 0.f) + 1e-7f;
            float p = __expf(m);
            s[k] += p; t[k] = fmaf(m, p, t[k]);
        }
        #pragma unroll
        for (int k = 0; k < 8; k++) {
            float m = fmaxf(bf2f((u16)r1.s[k]), 0.f) + 1e-7f;
            float p = __expf(m);
            s[k] += p; t[k] = fmaf(m, p, t[k]);
        }
    }
    // tail: up to 15 edges, per-lane predication (wave-uniform branches)
    int rem = je - j;
    if (rem > 0) {
        bool act = e < rem;
        int idx = esrc[j + (act ? e : rem - 1)];
        U4S8 r;
        r.u = *(const uint4*)&x[(size_t)idx * D_IN + cb];
        if (act) {
            #pragma unroll
            for (int k = 0; k < 8; k++) {
                float m = fmaxf(bf2f((u16)r.s[k]), 0.f) + 1e-7f;
                float p = __expf(m);
                s[k] += p; t[k] = fmaf(m, p, t[k]);
            }
        }
        if (rem > 8) {
            bool act2 = (e + 8) < rem;
            int idx2 = esrc[j + 8 + (act2 ? e : rem - 9)];
            U4S8 r2;
            r2.u = *(const uint4*)&x[(size_t)idx2 * D_IN + cb];
            if (act2) {
                #pragma unroll
                for (int k = 0; k < 8; k++) {
                    float m = fmaxf(bf2f((u16)r2.s[k]), 0.f) + 1e-7f;
                    float p = __expf(m);
                    s[k] += p; t[k] = fmaf(m, p, t[k]);
                }
            }
        }
    }
    // reduce across edge-slot lanes: lane^8 flips e bit0, ^16 bit1, ^32 bit2
    #pragma unroll
    for (int k = 0; k < 8; k++) {
        s[k] += __shfl_xor(s[k], 8);
        s[k] += __shfl_xor(s[k], 16);
        s[k] += __shfl_xor(s[k], 32);
        t[k] += __shfl_xor(t[k], 8);
        t[k] += __shfl_xor(t[k], 16);
        t[k] += __shfl_xor(t[k], 32);
    }
    if (e == 0) {  // lanes 0..7 hold all 64 channels
        U4S8 xr;
        xr.u = *(const uint4*)&x[(size_t)node * D_IN + cb];
        u32 w[4];
        #pragma unroll
        for (int k2 = 0; k2 < 4; k2++) {
            float v0 = t[2 * k2]     / (s[2 * k2]     + 1e-16f) + bf2f((u16)xr.s[2 * k2]);
            float v1 = t[2 * k2 + 1] / (s[2 * k2 + 1] + 1e-16f) + bf2f((u16)xr.s[2 * k2 + 1]);
            w[k2] = pk2(v0, v1);
        }
        *(uint4*)&h[(size_t)node * D_IN + cb] = make_uint4(w[0], w[1], w[2], w[3]);
    }
}

// ==================== GEMM1 (MFMA) + LDS-transpose epilogue + BN stats ========
// h1[M,128](bf16) = A[M,64](bf16) @ W1 + b1. 64 rows/block, 4 waves x 16 rows.
#define SC1 136  // u16 stride: 272 B = 17*16B (aligned for uint4 readback)
__global__ __launch_bounds__(256) void gemm1_kernel(const u16* __restrict__ A,
                                                    const u16* __restrict__ Wf,
                                                    const float* __restrict__ bias,
                                                    u16* __restrict__ Bout,
                                                    float* __restrict__ S,
                                                    float* __restrict__ Q) {
    __shared__ u16 sC[64 * SC1];  // 17.4 KB
    const int tid = threadIdx.x;
    const int wave = tid >> 6, ln = tid & 63;
    const int lm = ln & 15, quad = ln >> 4;
    const int row0g = blockIdx.x * 64;
    const int row0 = row0g + wave * 16;
    const int rA = min(row0 + lm, N_NODES - 1);

    // A-frags: A[m=lm][k=quad*8+j], two K=32 halves
    U4S8 a0, a1;
    a0.u = *(const uint4*)&A[(size_t)rA * 64 + quad * 8];
    a1.u = *(const uint4*)&A[(size_t)rA * 64 + 32 + quad * 8];

    f32x4 acc[8];
    #pragma unroll
    for (int t = 0; t < 8; t++) {
        float b = bias[t * 16 + lm];
        acc[t] = (f32x4){b, b, b, b};
    }
    #pragma unroll
    for (int t = 0; t < 8; t++) {
        U4S8 b0, b1;
        b0.u = *(const uint4*)&Wf[(size_t)((t * 2 + 0) * 64 + ln) * 8];
        b1.u = *(const uint4*)&Wf[(size_t)((t * 2 + 1) * 64 + ln) * 8];
        acc[t] = __builtin_amdgcn_mfma_f32_16x16x32_bf16(a0.s, b0.s, acc[t], 0, 0, 0);
        acc[t] = __builtin_amdgcn_mfma_f32_16x16x32_bf16(a1.s, b1.s, acc[t], 0, 0, 0);
    }
    // transpose through LDS (C-layout -> row-major bf16 tile)
    const int lr0 = wave * 16 + quad * 4;
    #pragma unroll
    for (int t = 0; t < 8; t++) {
        #pragma unroll
        for (int rg = 0; rg < 4; rg++)
            sC[(lr0 + rg) * SC1 + t * 16 + lm] = f2bf(acc[t][rg]);
    }
    __syncthreads();
    // coalesced vectorized store
    const int c8 = (tid & 15) * 8;
    #pragma unroll
    for (int i = 0; i < 4; i++) {
        int lr = (tid >> 4) + i * 16;
        int r = row0g + lr;
        if (r < N_NODES)
            *(uint4*)&Bout[(size_t)r * 128 + c8] = *(const uint4*)&sC[lr * SC1 + c8];
    }
    // BN stats: column scan, one atomic per column per block
    const int rlim = min(64, N_NODES - row0g);
    if (tid < 128) {
        float s = 0.f;
        #pragma unroll 8
        for (int r = 0; r < rlim; r++) s += bf2f(sC[r * SC1 + tid]);
        atomicAdd(&S[tid], s);
    } else {
        int c = tid - 128;
        float q = 0.f;
        #pragma unroll 8
        for (int r = 0; r < rlim; r++) { float v = bf2f(sC[r * SC1 + c]); q += v * v; }
        atomicAdd(&Q[c], q);
    }
}

// ==================== GEMM2 (MFMA) + fused BN finalize + LDS epilogue =========
__device__ __forceinline__ float mish_f(float v) {
    if (v > 30.f) return v;
    float u = __expf(v);
    float t = (u + 1.f) * (u + 1.f);
    return v * (t - 1.f) / (t + 1.f);  // = v * tanh(softplus(v))
}

#define SC2B 72  // u16 stride for bf16 tile: 144 B = 9*16B
#define SC2F 68  // f32 stride for fp32 tile: 272 B = 17*16B
__global__ __launch_bounds__(256) void gemm2_kernel(const u16* __restrict__ H,
                                                    const float* __restrict__ S,
                                                    const float* __restrict__ Q,
                                                    const float* __restrict__ gamma,
                                                    const float* __restrict__ beta,
                                                    const u16* __restrict__ Wf,
                                                    const float* __restrict__ bias,
                                                    float* __restrict__ outf,
                                                    u16* __restrict__ outb,
                                                    int dobf16) {
    __shared__ float sss[256];
    __shared__ __align__(16) char sCraw[64 * SC2F * 4];  // 17.4 KB
    u16* sCb = (u16*)sCraw;
    float* sCf = (float*)sCraw;
    const int tid = threadIdx.x;
    // fused BN finalize: per-channel scale/shift from global S/Q
    if (tid < 128) {
        float mean = S[tid] * (1.f / N_NODES);
        float var = fmaxf(Q[tid] * (1.f / N_NODES) - mean * mean, 0.f);
        float sc = gamma[tid] * rsqrtf(var + 1e-5f);
        sss[tid] = sc;
        sss[128 + tid] = beta[tid] - mean * sc;
    }
    __syncthreads();
    const int wave = tid >> 6, ln = tid & 63;
    const int lm = ln & 15, quad = ln >> 4;
    const int row0g = blockIdx.x * 64;
    const int row0 = row0g + wave * 16;
    const int rA = min(row0 + lm, N_NODES - 1);

    f32x4 acc[4];
    #pragma unroll
    for (int t = 0; t < 4; t++) {
        float b = bias[t * 16 + lm];
        acc[t] = (f32x4){b, b, b, b};
    }
    #pragma unroll
    for (int ks = 0; ks < 4; ks++) {
        const int k0 = ks * 32 + quad * 8;
        U4S8 h8;
        h8.u = *(const uint4*)&H[(size_t)rA * 128 + k0];
        U4S8 a;
        #pragma unroll
        for (int j2 = 0; j2 < 4; j2++) {
            int k = k0 + 2 * j2;
            float v0 = fmaxf(fmaf(bf2f((u16)h8.s[2 * j2]),     sss[k],     sss[128 + k]),     0.f);
            float v1 = fmaxf(fmaf(bf2f((u16)h8.s[2 * j2 + 1]), sss[k + 1], sss[128 + k + 1]), 0.f);
            ((u32*)&a.u)[j2] = pk2(v0, v1);
        }
        #pragma unroll
        for (int t = 0; t < 4; t++) {
            U4S8 b;
            b.u = *(const uint4*)&Wf[(size_t)((t * 4 + ks) * 64 + ln) * 8];
            acc[t] = __builtin_amdgcn_mfma_f32_16x16x32_bf16(a.s, b.s, acc[t], 0, 0, 0);
        }
    }
    const int lr0 = wave * 16 + quad * 4;
    if (dobf16) {
        #pragma unroll
        for (int t = 0; t < 4; t++) {
            #pragma unroll
            for (int rg = 0; rg < 4; rg++)
                sCb[(lr0 + rg) * SC2B + t * 16 + lm] = f2bf(mish_f(acc[t][rg]));
        }
        __syncthreads();
        const int c8 = (tid & 7) * 8;
        #pragma unroll
        for (int i = 0; i < 2; i++) {
            int lr = (tid >> 3) + i * 32;
            int r = row0g + lr;
            if (r < N_NODES)
                *(uint4*)&outb[(size_t)r * 64 + c8] = *(const uint4*)&sCb[lr * SC2B + c8];
        }
    } else {
        #pragma unroll
        for (int t = 0; t < 4; t++) {
            #pragma unroll
            for (int rg = 0; rg < 4; rg++)
                sCf[(lr0 + rg) * SC2F + t * 16 + lm] = acc[t][rg];
        }
        __syncthreads();
        const int c8 = (tid & 7) * 8;
        #pragma unroll
        for (int i = 0; i < 2; i++) {
            int lr = (tid >> 3) + i * 32;
            int r = row0g + lr;
            if (r < N_NODES) {
                *(float4*)&outf[(size_t)r * 64 + c8]     = *(const float4*)&sCf[lr * SC2F + c8];
                *(float4*)&outf[(size_t)r * 64 + c8 + 4] = *(const float4*)&sCf[lr * SC2F + c8 + 4];
            }
        }
    }
}

// ============================ launch ============================

extern "C" void kernel_launch(void* const* d_in, const int* in_sizes, int n_in,
                              void* d_out, int out_size, void* d_ws, size_t ws_size,
                              hipStream_t stream) {
    const float* x     = (const float*)d_in[0];
    const int*   ei    = (const int*)d_in[1];
    const float* W1    = (const float*)d_in[2];
    const float* b1    = (const float*)d_in[3];
    const float* gamma = (const float*)d_in[4];
    const float* beta  = (const float*)d_in[5];
    const float* W2    = (const float*)d_in[6];
    const float* b2    = (const float*)d_in[7];
    float* out = (float*)d_out;

    const int* src = ei;
    const int* dst = ei + N_EDGES;

    char* base = (char*)d_ws;
    size_t o = 0;
    auto take = [&](size_t bytes) -> char* {
        char* p = base + o;
        o = (o + bytes + 255) & ~(size_t)255;
        return p;
    };
    int* deg     = (int*)take((size_t)N_NODES * 4);
    int* off     = (int*)take((size_t)(N_NODES + 1) * 4);
    int* esrc    = (int*)take((size_t)N_EDGES * 4);
    int2* ebuf   = (int2*)take((size_t)N_EDGES * 8);
    int* bsum    = (int*)take((size_t)N_SB * 4);
    int* boff    = (int*)take((size_t)N_SB * 4);
    int* gcur    = (int*)take((size_t)NB * 4);
    float* bn    = (float*)take(1024 * 4);  // per layer: S[128] Q[128]
    u16* w1f     = (u16*)take((size_t)4 * 8192 * 2);  // W1 frags, 4 layers
    u16* w2f     = (u16*)take((size_t)4 * 8192 * 2);  // W2 frags, 4 layers
    u16* xbuf    = (u16*)take((size_t)N_NODES * D_IN * 2);   // bf16 hidden state
    u16* hbuf    = (u16*)take((size_t)N_NODES * D_IN * 2);   // bf16 agg output
    u16* h1buf   = (u16*)take((size_t)N_NODES * D_HID * 2);  // bf16 mid activations

    // CSR build (once per call; dst is layer-invariant)
    hipMemsetAsync(deg, 0, (size_t)N_NODES * 4, stream);
    hipMemsetAsync(bn, 0, 1024 * 4, stream);  // all layers' S/Q
    count_kernel<<<(N_EDGES + 255) / 256, 256, 0, stream>>>(dst, deg, N_EDGES);
    scan_reduce_kernel<<<N_SB, SCAN_B, 0, stream>>>(deg, bsum);
    scan_sums_kernel<<<1, SCAN_B, 0, stream>>>(bsum, boff);
    scan_write_kernel<<<N_SB, SCAN_B, 0, stream>>>(deg, boff, off);
    bin_init_kernel<<<1, 256, 0, stream>>>(off, gcur);
    bin_pass1_kernel<<<P1_BLOCKS, 256, 0, stream>>>(src, dst, gcur, ebuf);
    bin_pass2_kernel<<<NB, 256, 0, stream>>>(off, ebuf, esrc);
    xcvt_kernel<<<(N_NODES * D_IN / 4 + 255) / 256, 256, 0, stream>>>(x, xbuf);
    wprep_kernel<<<8, 256, 0, stream>>>(W1, W2, w1f, w2f);

    const int NBLK = (N_NODES + 63) / 64;
    const int ABLK = (N_NODES + 3) / 4;  // 1 node/wave, 4 waves/block
    for (int L = 0; L < 4; L++) {
        float* Sb = bn + L * 256;
        float* Qb = Sb + 128;
        agg_kernel<<<ABLK, 256, 0, stream>>>(xbuf, off, esrc, hbuf);
        gemm1_kernel<<<NBLK, 256, 0, stream>>>(
            hbuf, w1f + (size_t)L * 8192, b1 + (size_t)L * D_HID, h1buf,
            Sb, Qb);
        gemm2_kernel<<<NBLK, 256, 0, stream>>>(
            h1buf, Sb, Qb, gamma + (size_t)L * D_HID, beta + (size_t)L * D_HID,
            w2f + (size_t)L * 8192, b2 + (size_t)L * D_IN,
            out, xbuf, (L < 3) ? 1 : 0);
    }
}